// Round 10
// baseline (852.177 us; speedup 1.0000x reference)
//
#include <hip/hip_runtime.h>

#define NODES 100000
#define EDGES 100000
#define NR    100000       // rows per slice-major buffer (NODES==EDGES)
#define NNZV  1600000
#define NBK   196          // buckets per direction (512 rows each)
#define BKCAP 12288        // entry capacity per bucket (mean 8192)
#define TILE2 2048         // entries per partition block (256 thr x 8, both dirs)
#define NTIL2 782          // ceil(NNZV / TILE2)
#define NBGS  512          // gather blocks per slice-group

typedef unsigned short u16;
typedef __attribute__((ext_vector_type(8))) short bf16x8;   // 8 bf16 (4 VGPRs)
typedef __attribute__((ext_vector_type(4))) float f32x4;
typedef __attribute__((ext_vector_type(4))) unsigned short u16x4;

__device__ __forceinline__ float b2f(u16 h) {
  union { unsigned u; float f; } c; c.u = ((unsigned)h) << 16; return c.f;
}
__device__ __forceinline__ u16 f2b(float f) {
  union { unsigned u; float f; } c; c.f = f;
  unsigned u = c.u + 0x7FFF + ((c.u >> 16) & 1);   // round-to-nearest-even
  return (u16)(u >> 16);
}

// ============ W pre-transpose: W1T[n][128] = bf16(W1[k][n]), same for W2 ============
__global__ __launch_bounds__(256) void wtrans_kernel(const float* __restrict__ W1,
                                                     const float* __restrict__ W2,
                                                     u16* __restrict__ W1T, u16* __restrict__ W2T) {
  int i = blockIdx.x * 256 + threadIdx.x;
  if (i < 16384) {
    int k = i >> 7, n = i & 127;
    W1T[n * 128 + k] = f2b(W1[i]);
  } else if (i < 16384 + 8192) {
    int j = i - 16384;
    int k = j >> 6, n = j & 63;
    W2T[n * 128 + k] = f2b(W2[j]);
  }
}

// ====== K1: single-pass dual-direction partition into 2x196 row-range buckets ======
__global__ __launch_bounds__(256) void partition_kernel(const int* __restrict__ nidx,
                                                        const int* __restrict__ eidx,
                                                        int* __restrict__ gcnt,
                                                        unsigned* __restrict__ bk) {
  __shared__ int lcnt_e[NBK], lcnt_n[NBK], lbase_e[NBK], lbase_n[NBK];
  const int tid = threadIdx.x;
  const int j0 = blockIdx.x * TILE2;
  for (int i = tid; i < NBK; i += 256) { lcnt_e[i] = 0; lcnt_n[i] = 0; }
  __syncthreads();
  int be[8], bn[8]; unsigned pe[8], pn[8];
  #pragma unroll
  for (int i = 0; i < 8; i++) {
    int j = j0 + tid + i * 256;
    if (j < NNZV) {
      int e = __builtin_nontemporal_load(eidx + j);
      int n = __builtin_nontemporal_load(nidx + j);
      be[i] = e >> 9; pe[i] = ((unsigned)(e & 511) << 17) | (unsigned)n;
      bn[i] = n >> 9; pn[i] = ((unsigned)(n & 511) << 17) | (unsigned)e;
      atomicAdd(&lcnt_e[be[i]], 1);
      atomicAdd(&lcnt_n[bn[i]], 1);
    } else { be[i] = -1; bn[i] = -1; }
  }
  __syncthreads();
  for (int b = tid; b < NBK; b += 256) {
    int c = lcnt_e[b];
    lbase_e[b] = c ? atomicAdd(&gcnt[b], c) : 0;
    lcnt_e[b] = 0;
    c = lcnt_n[b];
    lbase_n[b] = c ? atomicAdd(&gcnt[NBK + b], c) : 0;
    lcnt_n[b] = 0;
  }
  __syncthreads();
  #pragma unroll
  for (int i = 0; i < 8; i++) {
    if (be[i] >= 0) {
      int p = lbase_e[be[i]] + atomicAdd(&lcnt_e[be[i]], 1);
      if (p < BKCAP) bk[(size_t)be[i] * BKCAP + p] = pe[i];
      p = lbase_n[bn[i]] + atomicAdd(&lcnt_n[bn[i]], 1);
      if (p < BKCAP) bk[(size_t)(NBK + bn[i]) * BKCAP + p] = pn[i];
    }
  }
}

// ===== K2: per-bucket counting sort -> off[] + col[]; scatter stays in hot L2 =====
__global__ __launch_bounds__(512) void bucket_sort_kernel(const int* __restrict__ gcnt,
                                                          const unsigned* __restrict__ bk,
                                                          int* __restrict__ off_e, int* __restrict__ off_v,
                                                          int* __restrict__ col_e, int* __restrict__ col_v) {
  const int gb = blockIdx.x;                       // 0..2*NBK-1
  const int dir = gb >= NBK ? 1 : 0;
  const int b = dir ? gb - NBK : gb;
  const int* __restrict__ cnt = gcnt + dir * NBK;
  const unsigned* __restrict__ bkd = bk + ((size_t)dir * NBK + b) * BKCAP;
  int* __restrict__ off = dir ? off_v : off_e;
  int* __restrict__ col = dir ? col_v : col_e;
  const int tid = threadIdx.x, lane = tid & 63, wid = tid >> 6;
  __shared__ int lcnt[512];
  __shared__ int wsum[8];
  __shared__ int base_s;
  if (tid < 64) {                                   // base = sum cnt[0..b)
    int s = 0;
    for (int t = tid; t < b; t += 64) s += cnt[t];
    #pragma unroll
    for (int d = 1; d < 64; d <<= 1) s += __shfl_xor(s, d);
    if (tid == 0) base_s = s;
  }
  lcnt[tid] = 0;
  __syncthreads();
  const int n = min(cnt[b], BKCAP);
  for (int i = tid; i < n; i += 512)
    atomicAdd(&lcnt[bkd[i] >> 17], 1);
  __syncthreads();
  int x = lcnt[tid];                                // per-row count
  int inc = x;
  #pragma unroll
  for (int d = 1; d < 64; d <<= 1) { int t = __shfl_up(inc, d); if (lane >= d) inc += t; }
  if (lane == 63) wsum[wid] = inc;
  __syncthreads();
  int wbase = 0;
  for (int k = 0; k < wid; k++) wbase += wsum[k];
  const int gpos = base_s + wbase + inc - x;        // global exclusive position for row tid
  const int row = (b << 9) + tid;
  if (row < NODES) off[row] = gpos;
  if (b == NBK - 1 && tid == 0) off[NODES] = NNZV;
  __syncthreads();
  lcnt[tid] = gpos;                                 // cursor = global position
  __syncthreads();
  for (int i = tid; i < n; i += 512) {
    unsigned e = bkd[i];
    int p = atomicAdd(&lcnt[e >> 17], 1);
    col[p] = (int)(e & 0x1FFFFu);
  }
}

// ======= MFMA GEMM: Y(slice-major, OS feats/slice) = X[M,128] @ W[128,N] =======
// XBF=0: X is f32 row-major. XBF=1: X is bf16 slice-major [8][NR][16].
template<int N, bool XBF, int OS>
__global__ __launch_bounds__(256) void gemm_kernel(const void* __restrict__ Xv,
                                                   const u16* __restrict__ WT,
                                                   u16* __restrict__ Y, int M) {
  __shared__ u16 sX[64 * 136];
  __shared__ u16 sW[N * 136];
  const int tid = threadIdx.x, lane = tid & 63, w = tid >> 6;
  const int chunk = blockIdx.x * 64;
  constexpr int WV = N * 128 / 8;
  for (int t = tid; t < WV; t += 256) {
    int e = t * 8, n = e >> 7, k = e & 127;
    *(bf16x8*)(sW + n * 136 + k) = *(const bf16x8*)(WT + n * 128 + k);
  }
  if constexpr (XBF) {
    const u16* X = (const u16*)Xv;                  // slice-major [8][NR][16]
    for (int t = tid; t < 1024; t += 256) {
      int ss = t >> 7;                              // slice
      int u = t & 127;
      int r = u >> 1, half = u & 1;
      int row = min(chunk + r, M - 1);
      *(bf16x8*)(sX + r * 136 + ss * 16 + half * 8) =
          *(const bf16x8*)(X + (size_t)ss * NR * 16 + (size_t)row * 16 + half * 8);
    }
  } else {
    const float* X = (const float*)Xv;
    for (int t = tid; t < 2048; t += 256) {
      int r = t >> 5, c4 = t & 31;
      int row = min(chunk + r, M - 1);
      float4 v = *(const float4*)(X + (size_t)row * 128 + c4 * 4);
      ushort4 o = { f2b(v.x), f2b(v.y), f2b(v.z), f2b(v.w) };
      *(ushort4*)(sX + r * 136 + c4 * 4) = o;
    }
  }
  __syncthreads();
  constexpr int CW = N / 2;
  constexpr int NT = CW / 16;
  const int wr = w >> 1, wc = w & 1;
  const int l15 = lane & 15;
  const int arow = wr * 32 + l15;
  const int kb = (lane >> 4) * 8;
  f32x4 acc[2][NT];
  #pragma unroll
  for (int rt = 0; rt < 2; rt++)
    #pragma unroll
    for (int nt = 0; nt < NT; nt++) acc[rt][nt] = (f32x4){0.f, 0.f, 0.f, 0.f};
  #pragma unroll
  for (int kk = 0; kk < 4; kk++) {
    const int ko = kk * 32 + kb;
    bf16x8 a0 = *(const bf16x8*)(sX + arow * 136 + ko);
    bf16x8 a1 = *(const bf16x8*)(sX + (arow + 16) * 136 + ko);
    #pragma unroll
    for (int nt = 0; nt < NT; nt++) {
      bf16x8 bb = *(const bf16x8*)(sW + (wc * CW + nt * 16 + l15) * 136 + ko);
      acc[0][nt] = __builtin_amdgcn_mfma_f32_16x16x32_bf16(a0, bb, acc[0][nt], 0, 0, 0);
      acc[1][nt] = __builtin_amdgcn_mfma_f32_16x16x32_bf16(a1, bb, acc[1][nt], 0, 0, 0);
    }
  }
  const int r4 = (lane >> 4) * 4;
  #pragma unroll
  for (int rt = 0; rt < 2; rt++)
    #pragma unroll
    for (int r = 0; r < 4; r++) {
      int row = chunk + wr * 32 + rt * 16 + r4 + r;
      if (row < M) {
        #pragma unroll
        for (int nt = 0; nt < NT; nt++) {
          int cn = wc * CW + nt * 16 + l15;
          int sl = cn / OS, fi = cn % OS;
          Y[(size_t)sl * NR * OS + (size_t)row * OS + fi] = f2b(acc[rt][nt][r]);
        }
      }
    }
}

// ===== XCD-sliced gather: group s (blockIdx%8 -> XCD s) does slice s for ALL rows =====
// src slice-major [8][NR][SLICE] bf16. dst: bf16 slice-major, or f32 row-major (F32OUT).
// Wave handles 4 rows; lane = (member-slot g, 4-feat block l).
template<int F, bool HASB, bool RELU, bool F32OUT>
__global__ __launch_bounds__(256) void gatherS_kernel(const int* __restrict__ off,
                                                      const int* __restrict__ col,
                                                      const u16* __restrict__ src,
                                                      const float* __restrict__ bias,
                                                      void* __restrict__ dstv, int nrows) {
  constexpr int SLICE = F / 8;              // feats per slice: 16 or 8
  constexpr int LPM   = SLICE / 4;          // lanes per member: 4 or 2
  constexpr int SLOTS = 64 / LPM;           // member slots: 16 or 32
  constexpr int NB0   = (F == 128) ? 2 : 1; // upfront predicated batches
  const int s = blockIdx.x & 7;             // slice / XCD group
  const int b = blockIdx.x >> 3;
  const int lane = threadIdx.x & 63, wave = threadIdx.x >> 6;
  const int g = lane / LPM;
  const int l = lane % LPM;
  const u16* __restrict__ srcS = src + (size_t)s * NR * SLICE;
  float bi[4];
  if constexpr (HASB) {
    #pragma unroll
    for (int t = 0; t < 4; t++) bi[t] = bias[s * SLICE + l * 4 + t];
  }
  for (int row0 = b * 16 + wave * 4; row0 < nrows; row0 += NBGS * 16) {
    int s0a[4], s1a[4];
    #pragma unroll
    for (int rr = 0; rr < 4; rr++) {
      int row = row0 + rr;
      s0a[rr] = (row < nrows) ? off[row] : 0;
      s1a[rr] = (row < nrows) ? off[row + 1] : 0;
    }
    float acc[4][4] = {};
    // upfront batches for all 4 rows (loads independent -> MLP)
    #pragma unroll
    for (int bb = 0; bb < NB0; bb++) {
      int ia[4]; ushort4 va[4];
      #pragma unroll
      for (int rr = 0; rr < 4; rr++) {
        ia[rr] = s0a[rr] + bb * SLOTS + g;
        int c = __builtin_nontemporal_load(col + min(ia[rr], NNZV - 1));
        va[rr] = *(const ushort4*)(srcS + (size_t)c * SLICE + l * 4);
      }
      #pragma unroll
      for (int rr = 0; rr < 4; rr++)
        if (ia[rr] < s1a[rr]) {
          acc[rr][0] += b2f(va[rr].x); acc[rr][1] += b2f(va[rr].y);
          acc[rr][2] += b2f(va[rr].z); acc[rr][3] += b2f(va[rr].w);
        }
    }
    // rare leftovers (deg > NB0*SLOTS)
    #pragma unroll
    for (int rr = 0; rr < 4; rr++) {
      for (int k = s0a[rr] + NB0 * SLOTS; k < s1a[rr]; k += SLOTS) {
        int idx = k + g;
        int c = __builtin_nontemporal_load(col + min(idx, NNZV - 1));
        ushort4 v = *(const ushort4*)(srcS + (size_t)c * SLICE + l * 4);
        if (idx < s1a[rr]) {
          acc[rr][0] += b2f(v.x); acc[rr][1] += b2f(v.y);
          acc[rr][2] += b2f(v.z); acc[rr][3] += b2f(v.w);
        }
      }
    }
    // reduce across member slots (xor of multiples of LPM preserves l)
    #pragma unroll
    for (int rr = 0; rr < 4; rr++)
      #pragma unroll
      for (int d = LPM; d < 64; d <<= 1)
        #pragma unroll
        for (int t = 0; t < 4; t++) acc[rr][t] += __shfl_xor(acc[rr][t], d);
    if (g == 0) {
      #pragma unroll
      for (int rr = 0; rr < 4; rr++) {
        int row = row0 + rr;
        if (row >= nrows) continue;
        const float sc = (s1a[rr] > s0a[rr]) ? 1.0f / (float)(s1a[rr] - s0a[rr]) : 0.f;
        float v[4];
        #pragma unroll
        for (int t = 0; t < 4; t++) {
          v[t] = acc[rr][t] * sc;
          if constexpr (HASB) v[t] += bi[t];
          if constexpr (RELU) v[t] = fmaxf(v[t], 0.f);
        }
        if constexpr (F32OUT) {
          f32x4 o = {v[0], v[1], v[2], v[3]};
          __builtin_nontemporal_store(o, (f32x4*)((float*)dstv + (size_t)row * 64 + s * 8 + l * 4));
        } else {
          u16x4 o = {f2b(v[0]), f2b(v[1]), f2b(v[2]), f2b(v[3])};
          __builtin_nontemporal_store(o, (u16x4*)((u16*)dstv + (size_t)s * NR * SLICE + (size_t)row * SLICE + l * 4));
        }
      }
    }
  }
}

extern "C" void kernel_launch(void* const* d_in, const int* in_sizes, int n_in,
                              void* d_out, int out_size, void* d_ws, size_t ws_size,
                              hipStream_t stream) {
  const float* x  = (const float*)d_in[0];
  const int*   hi = (const int*)d_in[1];
  const float* W1 = (const float*)d_in[2];
  const float* b1 = (const float*)d_in[3];
  const float* W2 = (const float*)d_in[4];
  const float* b2 = (const float*)d_in[5];
  float* out = (float*)d_out;
  const int* nidx = hi;             // row 0: node indices
  const int* eidx = hi + NNZV;      // row 1: edge indices

  char* w = (char*)d_ws;
  int*      off_e = (int*)w;                           // 100001 ints
  int*      off_v = (int*)(w + 524288);                // 100001 ints
  int*      gcnt  = (int*)(w + 1048576);               // 392 ints
  u16*      W1T   = (u16*)(w + 1052672);               // 128x128 bf16
  u16*      W2T   = (u16*)(w + 1085440);               // 64x128 bf16
  int*      col_e = (int*)(w + 2097152);               // 1.6M ints
  int*      col_v = (int*)(w + 8650752);               // 1.6M ints
  unsigned* bk    = (unsigned*)(w + 16777216);         // 19.3 MB
  u16*      bufH  = (u16*)(w + 56623104);              // 25.6 MB: h1 / h2 / m2e (slice-major)
  u16*      bufM  = (u16*)(w + 56623104 + 25600000);   // 25.6 MB: m_e / g2 (slice-major)

  // ---- weight pre-transpose + CSR build ----
  hipMemsetAsync(gcnt, 0, 392 * 4, stream);
  wtrans_kernel<<<96, 256, 0, stream>>>(W1, W2, W1T, W2T);
  partition_kernel<<<NTIL2, 256, 0, stream>>>(nidx, eidx, gcnt, bk);
  bucket_sort_kernel<<<2 * NBK, 512, 0, stream>>>(gcnt, bk, off_e, off_v, col_e, col_v);

  // ---- conv1 (F=128, slice-major SLICE=16) ----
  gemm_kernel<128, false, 16><<<1563, 256, 0, stream>>>(x, W1T, bufH, NODES);      // h1
  gatherS_kernel<128, false, false, false><<<8 * NBGS, 256, 0, stream>>>(
      off_e, col_e, bufH, nullptr, bufM, EDGES);                                   // m_e
  gatherS_kernel<128, true, true, false><<<8 * NBGS, 256, 0, stream>>>(
      off_v, col_v, bufM, b1, bufH, NODES);                                        // h2
  // ---- conv2 (F=64, slice-major SLICE=8) ----
  gemm_kernel<64, true, 8><<<1563, 256, 0, stream>>>(bufH, W2T, bufM, NODES);      // g2
  gatherS_kernel<64, false, false, false><<<8 * NBGS, 256, 0, stream>>>(
      off_e, col_e, bufM, nullptr, bufH, EDGES);                                   // m2e
  gatherS_kernel<64, true, false, true><<<8 * NBGS, 256, 0, stream>>>(
      off_v, col_v, bufH, b2, out, NODES);                                         // out(f32)
}

// Round 11
// 550.098 us; speedup vs baseline: 1.5491x; 1.5491x over previous
//
#include <hip/hip_runtime.h>

#define NODES 100000
#define EDGES 100000
#define NR    100000       // rows per slice-major buffer (NODES==EDGES)
#define NNZV  1600000
#define NBK   196          // buckets per direction (512 rows each)
#define BKCAP 12288        // entry capacity per bucket (mean 8192)
#define TILE2 2048         // entries per partition block (256 thr x 8, both dirs)
#define NTIL2 782          // ceil(NNZV / TILE2)
#define NBGS  512          // gather blocks per slice-group

typedef unsigned short u16;
typedef __attribute__((ext_vector_type(8))) short bf16x8;   // 8 bf16 (4 VGPRs)
typedef __attribute__((ext_vector_type(4))) float f32x4;

__device__ __forceinline__ float b2f(u16 h) {
  union { unsigned u; float f; } c; c.u = ((unsigned)h) << 16; return c.f;
}
__device__ __forceinline__ u16 f2b(float f) {
  union { unsigned u; float f; } c; c.f = f;
  unsigned u = c.u + 0x7FFF + ((c.u >> 16) & 1);   // round-to-nearest-even
  return (u16)(u >> 16);
}

// ============ W pre-transpose: W1T[n][128] = bf16(W1[k][n]), same for W2 ============
__global__ __launch_bounds__(256) void wtrans_kernel(const float* __restrict__ W1,
                                                     const float* __restrict__ W2,
                                                     u16* __restrict__ W1T, u16* __restrict__ W2T) {
  int i = blockIdx.x * 256 + threadIdx.x;
  if (i < 16384) {
    int k = i >> 7, n = i & 127;
    W1T[n * 128 + k] = f2b(W1[i]);
  } else if (i < 16384 + 8192) {
    int j = i - 16384;
    int k = j >> 6, n = j & 63;
    W2T[n * 128 + k] = f2b(W2[j]);
  }
}

// ====== K1: single-pass dual-direction partition into 2x196 row-range buckets ======
__global__ __launch_bounds__(256) void partition_kernel(const int* __restrict__ nidx,
                                                        const int* __restrict__ eidx,
                                                        int* __restrict__ gcnt,
                                                        unsigned* __restrict__ bk) {
  __shared__ int lcnt_e[NBK], lcnt_n[NBK], lbase_e[NBK], lbase_n[NBK];
  const int tid = threadIdx.x;
  const int j0 = blockIdx.x * TILE2;
  for (int i = tid; i < NBK; i += 256) { lcnt_e[i] = 0; lcnt_n[i] = 0; }
  __syncthreads();
  int be[8], bn[8]; unsigned pe[8], pn[8];
  #pragma unroll
  for (int i = 0; i < 8; i++) {
    int j = j0 + tid + i * 256;
    if (j < NNZV) {
      int e = __builtin_nontemporal_load(eidx + j);
      int n = __builtin_nontemporal_load(nidx + j);
      be[i] = e >> 9; pe[i] = ((unsigned)(e & 511) << 17) | (unsigned)n;
      bn[i] = n >> 9; pn[i] = ((unsigned)(n & 511) << 17) | (unsigned)e;
      atomicAdd(&lcnt_e[be[i]], 1);
      atomicAdd(&lcnt_n[bn[i]], 1);
    } else { be[i] = -1; bn[i] = -1; }
  }
  __syncthreads();
  for (int b = tid; b < NBK; b += 256) {
    int c = lcnt_e[b];
    lbase_e[b] = c ? atomicAdd(&gcnt[b], c) : 0;
    lcnt_e[b] = 0;
    c = lcnt_n[b];
    lbase_n[b] = c ? atomicAdd(&gcnt[NBK + b], c) : 0;
    lcnt_n[b] = 0;
  }
  __syncthreads();
  #pragma unroll
  for (int i = 0; i < 8; i++) {
    if (be[i] >= 0) {
      int p = lbase_e[be[i]] + atomicAdd(&lcnt_e[be[i]], 1);
      if (p < BKCAP) bk[(size_t)be[i] * BKCAP + p] = pe[i];
      p = lbase_n[bn[i]] + atomicAdd(&lcnt_n[bn[i]], 1);
      if (p < BKCAP) bk[(size_t)(NBK + bn[i]) * BKCAP + p] = pn[i];
    }
  }
}

// ===== K2: per-bucket counting sort -> off[] + col[]; scatter stays in hot L2 =====
__global__ __launch_bounds__(512) void bucket_sort_kernel(const int* __restrict__ gcnt,
                                                          const unsigned* __restrict__ bk,
                                                          int* __restrict__ off_e, int* __restrict__ off_v,
                                                          int* __restrict__ col_e, int* __restrict__ col_v) {
  const int gb = blockIdx.x;                       // 0..2*NBK-1
  const int dir = gb >= NBK ? 1 : 0;
  const int b = dir ? gb - NBK : gb;
  const int* __restrict__ cnt = gcnt + dir * NBK;
  const unsigned* __restrict__ bkd = bk + ((size_t)dir * NBK + b) * BKCAP;
  int* __restrict__ off = dir ? off_v : off_e;
  int* __restrict__ col = dir ? col_v : col_e;
  const int tid = threadIdx.x, lane = tid & 63, wid = tid >> 6;
  __shared__ int lcnt[512];
  __shared__ int wsum[8];
  __shared__ int base_s;
  if (tid < 64) {                                   // base = sum cnt[0..b)
    int s = 0;
    for (int t = tid; t < b; t += 64) s += cnt[t];
    #pragma unroll
    for (int d = 1; d < 64; d <<= 1) s += __shfl_xor(s, d);
    if (tid == 0) base_s = s;
  }
  lcnt[tid] = 0;
  __syncthreads();
  const int n = min(cnt[b], BKCAP);
  for (int i = tid; i < n; i += 512)
    atomicAdd(&lcnt[bkd[i] >> 17], 1);
  __syncthreads();
  int x = lcnt[tid];                                // per-row count
  int inc = x;
  #pragma unroll
  for (int d = 1; d < 64; d <<= 1) { int t = __shfl_up(inc, d); if (lane >= d) inc += t; }
  if (lane == 63) wsum[wid] = inc;
  __syncthreads();
  int wbase = 0;
  for (int k = 0; k < wid; k++) wbase += wsum[k];
  const int gpos = base_s + wbase + inc - x;        // global exclusive position for row tid
  const int row = (b << 9) + tid;
  if (row < NODES) off[row] = gpos;
  if (b == NBK - 1 && tid == 0) off[NODES] = NNZV;
  __syncthreads();
  lcnt[tid] = gpos;                                 // cursor = global position
  __syncthreads();
  for (int i = tid; i < n; i += 512) {
    unsigned e = bkd[i];
    int p = atomicAdd(&lcnt[e >> 17], 1);
    col[p] = (int)(e & 0x1FFFFu);
  }
}

// ======= MFMA GEMM: Y(slice-major, OS feats/slice) = X[M,128] @ W[128,N] =======
// XBF=0: X is f32 row-major. XBF=1: X is bf16 slice-major [8][NR][16].
template<int N, bool XBF, int OS>
__global__ __launch_bounds__(256) void gemm_kernel(const void* __restrict__ Xv,
                                                   const u16* __restrict__ WT,
                                                   u16* __restrict__ Y, int M) {
  __shared__ u16 sX[64 * 136];
  __shared__ u16 sW[N * 136];
  const int tid = threadIdx.x, lane = tid & 63, w = tid >> 6;
  const int chunk = blockIdx.x * 64;
  constexpr int WV = N * 128 / 8;
  for (int t = tid; t < WV; t += 256) {
    int e = t * 8, n = e >> 7, k = e & 127;
    *(bf16x8*)(sW + n * 136 + k) = *(const bf16x8*)(WT + n * 128 + k);
  }
  if constexpr (XBF) {
    const u16* X = (const u16*)Xv;                  // slice-major [8][NR][16]
    for (int t = tid; t < 1024; t += 256) {
      int ss = t >> 7;                              // slice
      int u = t & 127;
      int r = u >> 1, half = u & 1;
      int row = min(chunk + r, M - 1);
      *(bf16x8*)(sX + r * 136 + ss * 16 + half * 8) =
          *(const bf16x8*)(X + (size_t)ss * NR * 16 + (size_t)row * 16 + half * 8);
    }
  } else {
    const float* X = (const float*)Xv;
    for (int t = tid; t < 2048; t += 256) {
      int r = t >> 5, c4 = t & 31;
      int row = min(chunk + r, M - 1);
      float4 v = *(const float4*)(X + (size_t)row * 128 + c4 * 4);
      ushort4 o = { f2b(v.x), f2b(v.y), f2b(v.z), f2b(v.w) };
      *(ushort4*)(sX + r * 136 + c4 * 4) = o;
    }
  }
  __syncthreads();
  constexpr int CW = N / 2;
  constexpr int NT = CW / 16;
  const int wr = w >> 1, wc = w & 1;
  const int l15 = lane & 15;
  const int arow = wr * 32 + l15;
  const int kb = (lane >> 4) * 8;
  f32x4 acc[2][NT];
  #pragma unroll
  for (int rt = 0; rt < 2; rt++)
    #pragma unroll
    for (int nt = 0; nt < NT; nt++) acc[rt][nt] = (f32x4){0.f, 0.f, 0.f, 0.f};
  #pragma unroll
  for (int kk = 0; kk < 4; kk++) {
    const int ko = kk * 32 + kb;
    bf16x8 a0 = *(const bf16x8*)(sX + arow * 136 + ko);
    bf16x8 a1 = *(const bf16x8*)(sX + (arow + 16) * 136 + ko);
    #pragma unroll
    for (int nt = 0; nt < NT; nt++) {
      bf16x8 bb = *(const bf16x8*)(sW + (wc * CW + nt * 16 + l15) * 136 + ko);
      acc[0][nt] = __builtin_amdgcn_mfma_f32_16x16x32_bf16(a0, bb, acc[0][nt], 0, 0, 0);
      acc[1][nt] = __builtin_amdgcn_mfma_f32_16x16x32_bf16(a1, bb, acc[1][nt], 0, 0, 0);
    }
  }
  const int r4 = (lane >> 4) * 4;
  #pragma unroll
  for (int rt = 0; rt < 2; rt++)
    #pragma unroll
    for (int r = 0; r < 4; r++) {
      int row = chunk + wr * 32 + rt * 16 + r4 + r;
      if (row < M) {
        #pragma unroll
        for (int nt = 0; nt < NT; nt++) {
          int cn = wc * CW + nt * 16 + l15;
          int sl = cn / OS, fi = cn % OS;
          Y[(size_t)sl * NR * OS + (size_t)row * OS + fi] = f2b(acc[rt][nt][r]);
        }
      }
    }
}

// ===== lean XCD-sliced gather: group s (blockIdx%8 -> XCD s) does slice s, all rows =====
// Wave = 8 rows x 8 lanes. Per row: SLOTS member-slots x LPM lanes, 16B bf16x8 loads,
// exact-deg divergent loop (2 loads in flight), 2-3 shfl levels amortized over 8 rows.
// src slice-major [8][NR][SLICE] bf16; dst bf16 slice-major or f32 row-major (F32OUT).
template<int F, bool HASB, bool RELU, bool F32OUT>
__global__ __launch_bounds__(256) void gatherS_kernel(const int* __restrict__ off,
                                                      const int* __restrict__ col,
                                                      const u16* __restrict__ src,
                                                      const float* __restrict__ bias,
                                                      void* __restrict__ dstv, int nrows) {
  constexpr int SLICE = F / 8;              // feats per slice: 16 or 8
  constexpr int LPM   = SLICE / 8;          // lanes per member: 2 or 1
  constexpr int SLOTS = 8 / LPM;            // member slots per row: 4 or 8
  const int s = blockIdx.x & 7;             // slice / XCD group
  const int b = blockIdx.x >> 3;
  const int lane = threadIdx.x & 63, wave = threadIdx.x >> 6;
  const int r = lane >> 3;                  // row within wave (0..7)
  const int p = lane & 7;
  const int slot = p / LPM;
  const int l = p % LPM;                    // 8-feat half within slice
  const u16* __restrict__ srcS = src + (size_t)s * NR * SLICE;
  float bi[8];
  if constexpr (HASB) {
    #pragma unroll
    for (int t = 0; t < 8; t++) bi[t] = bias[s * SLICE + l * 8 + t];
  }
  for (int row0 = b * 32 + wave * 8; row0 < nrows; row0 += NBGS * 32) {
    const int row = row0 + r;
    const bool act = row < nrows;
    const int s0 = act ? off[row] : 0;
    const int s1 = act ? off[row + 1] : 0;
    float acc[8] = {};
    int k = s0 + slot;
    while (k + SLOTS < s1) {                // 2 member loads in flight per lane
      int c0 = __builtin_nontemporal_load(col + k);
      int c1 = __builtin_nontemporal_load(col + k + SLOTS);
      bf16x8 v0 = *(const bf16x8*)(srcS + (size_t)c0 * SLICE + l * 8);
      bf16x8 v1 = *(const bf16x8*)(srcS + (size_t)c1 * SLICE + l * 8);
      #pragma unroll
      for (int t = 0; t < 8; t++) acc[t] += b2f((u16)v0[t]);
      #pragma unroll
      for (int t = 0; t < 8; t++) acc[t] += b2f((u16)v1[t]);
      k += 2 * SLOTS;
    }
    if (k < s1) {
      int c0 = __builtin_nontemporal_load(col + k);
      bf16x8 v0 = *(const bf16x8*)(srcS + (size_t)c0 * SLICE + l * 8);
      #pragma unroll
      for (int t = 0; t < 8; t++) acc[t] += b2f((u16)v0[t]);
    }
    // reduce across slots (xor within the 8-lane row group; preserves l and r)
    #pragma unroll
    for (int d = LPM; d < 8; d <<= 1)
      #pragma unroll
      for (int t = 0; t < 8; t++) acc[t] += __shfl_xor(acc[t], d);
    if (slot == 0 && act) {
      const float sc = (s1 > s0) ? 1.0f / (float)(s1 - s0) : 0.f;
      float v[8];
      #pragma unroll
      for (int t = 0; t < 8; t++) {
        v[t] = acc[t] * sc;
        if constexpr (HASB) v[t] += bi[t];
        if constexpr (RELU) v[t] = fmaxf(v[t], 0.f);
      }
      if constexpr (F32OUT) {
        float* d = (float*)dstv + (size_t)row * 64 + s * 8 + l * 8;
        f32x4 o0 = {v[0], v[1], v[2], v[3]};
        f32x4 o1 = {v[4], v[5], v[6], v[7]};
        __builtin_nontemporal_store(o0, (f32x4*)d);
        __builtin_nontemporal_store(o1, (f32x4*)(d + 4));
      } else {
        bf16x8 o;
        #pragma unroll
        for (int t = 0; t < 8; t++) o[t] = (short)f2b(v[t]);
        __builtin_nontemporal_store(
            o, (bf16x8*)((u16*)dstv + (size_t)s * NR * SLICE + (size_t)row * SLICE + l * 8));
      }
    }
  }
}

extern "C" void kernel_launch(void* const* d_in, const int* in_sizes, int n_in,
                              void* d_out, int out_size, void* d_ws, size_t ws_size,
                              hipStream_t stream) {
  const float* x  = (const float*)d_in[0];
  const int*   hi = (const int*)d_in[1];
  const float* W1 = (const float*)d_in[2];
  const float* b1 = (const float*)d_in[3];
  const float* W2 = (const float*)d_in[4];
  const float* b2 = (const float*)d_in[5];
  float* out = (float*)d_out;
  const int* nidx = hi;             // row 0: node indices
  const int* eidx = hi + NNZV;      // row 1: edge indices

  char* w = (char*)d_ws;
  int*      off_e = (int*)w;                           // 100001 ints
  int*      off_v = (int*)(w + 524288);                // 100001 ints
  int*      gcnt  = (int*)(w + 1048576);               // 392 ints
  u16*      W1T   = (u16*)(w + 1052672);               // 128x128 bf16
  u16*      W2T   = (u16*)(w + 1085440);               // 64x128 bf16
  int*      col_e = (int*)(w + 2097152);               // 1.6M ints
  int*      col_v = (int*)(w + 8650752);               // 1.6M ints
  unsigned* bk    = (unsigned*)(w + 16777216);         // 19.3 MB
  u16*      bufH  = (u16*)(w + 56623104);              // 25.6 MB: h1 / h2 / m2e (slice-major)
  u16*      bufM  = (u16*)(w + 56623104 + 25600000);   // 25.6 MB: m_e / g2 (slice-major)

  // ---- weight pre-transpose + CSR build ----
  hipMemsetAsync(gcnt, 0, 392 * 4, stream);
  wtrans_kernel<<<96, 256, 0, stream>>>(W1, W2, W1T, W2T);
  partition_kernel<<<NTIL2, 256, 0, stream>>>(nidx, eidx, gcnt, bk);
  bucket_sort_kernel<<<2 * NBK, 512, 0, stream>>>(gcnt, bk, off_e, off_v, col_e, col_v);

  // ---- conv1 (F=128, slice-major SLICE=16) ----
  gemm_kernel<128, false, 16><<<1563, 256, 0, stream>>>(x, W1T, bufH, NODES);      // h1
  gatherS_kernel<128, false, false, false><<<8 * NBGS, 256, 0, stream>>>(
      off_e, col_e, bufH, nullptr, bufM, EDGES);                                   // m_e
  gatherS_kernel<128, true, true, false><<<8 * NBGS, 256, 0, stream>>>(
      off_v, col_v, bufM, b1, bufH, NODES);                                        // h2
  // ---- conv2 (F=64, slice-major SLICE=8) ----
  gemm_kernel<64, true, 8><<<1563, 256, 0, stream>>>(bufH, W2T, bufM, NODES);      // g2
  gatherS_kernel<64, false, false, false><<<8 * NBGS, 256, 0, stream>>>(
      off_e, col_e, bufM, nullptr, bufH, EDGES);                                   // m2e
  gatherS_kernel<64, true, false, true><<<8 * NBGS, 256, 0, stream>>>(
      off_v, col_v, bufH, b2, out, NODES);                                         // out(f32)
}

// Round 12
// 385.373 us; speedup vs baseline: 2.2113x; 1.4274x over previous
//
#include <hip/hip_runtime.h>

#define NODES 100000
#define EDGES 100000
#define NR    100000       // rows per slice-major buffer (NODES==EDGES)
#define NNZV  1600000
#define NBK   196          // buckets per direction (512 rows each)
#define BKCAP 12288        // entry capacity per bucket (mean 8192)
#define TILE2 2048         // entries per partition block (256 thr x 8, both dirs)
#define NTIL2 782          // ceil(NNZV / TILE2)
#define NBGS  512          // gather blocks per slice-group

typedef unsigned short u16;
typedef __attribute__((ext_vector_type(8))) short bf16x8;   // 8 bf16 (4 VGPRs)
typedef __attribute__((ext_vector_type(4))) float f32x4;

__device__ __forceinline__ float b2f(u16 h) {
  union { unsigned u; float f; } c; c.u = ((unsigned)h) << 16; return c.f;
}
__device__ __forceinline__ u16 f2b(float f) {
  union { unsigned u; float f; } c; c.f = f;
  unsigned u = c.u + 0x7FFF + ((c.u >> 16) & 1);   // round-to-nearest-even
  return (u16)(u >> 16);
}

// ============ W pre-transpose: W1T[n][128] = bf16(W1[k][n]), same for W2 ============
__global__ __launch_bounds__(256) void wtrans_kernel(const float* __restrict__ W1,
                                                     const float* __restrict__ W2,
                                                     u16* __restrict__ W1T, u16* __restrict__ W2T) {
  int i = blockIdx.x * 256 + threadIdx.x;
  if (i < 16384) {
    int k = i >> 7, n = i & 127;
    W1T[n * 128 + k] = f2b(W1[i]);
  } else if (i < 16384 + 8192) {
    int j = i - 16384;
    int k = j >> 6, n = j & 63;
    W2T[n * 128 + k] = f2b(W2[j]);
  }
}

// ====== K1: single-pass dual-direction partition into 2x196 row-range buckets ======
__global__ __launch_bounds__(256) void partition_kernel(const int* __restrict__ nidx,
                                                        const int* __restrict__ eidx,
                                                        int* __restrict__ gcnt,
                                                        unsigned* __restrict__ bk) {
  __shared__ int lcnt_e[NBK], lcnt_n[NBK], lbase_e[NBK], lbase_n[NBK];
  const int tid = threadIdx.x;
  const int j0 = blockIdx.x * TILE2;
  for (int i = tid; i < NBK; i += 256) { lcnt_e[i] = 0; lcnt_n[i] = 0; }
  __syncthreads();
  int be[8], bn[8]; unsigned pe[8], pn[8];
  #pragma unroll
  for (int i = 0; i < 8; i++) {
    int j = j0 + tid + i * 256;
    if (j < NNZV) {
      int e = __builtin_nontemporal_load(eidx + j);
      int n = __builtin_nontemporal_load(nidx + j);
      be[i] = e >> 9; pe[i] = ((unsigned)(e & 511) << 17) | (unsigned)n;
      bn[i] = n >> 9; pn[i] = ((unsigned)(n & 511) << 17) | (unsigned)e;
      atomicAdd(&lcnt_e[be[i]], 1);
      atomicAdd(&lcnt_n[bn[i]], 1);
    } else { be[i] = -1; bn[i] = -1; }
  }
  __syncthreads();
  for (int b = tid; b < NBK; b += 256) {
    int c = lcnt_e[b];
    lbase_e[b] = c ? atomicAdd(&gcnt[b], c) : 0;
    lcnt_e[b] = 0;
    c = lcnt_n[b];
    lbase_n[b] = c ? atomicAdd(&gcnt[NBK + b], c) : 0;
    lcnt_n[b] = 0;
  }
  __syncthreads();
  #pragma unroll
  for (int i = 0; i < 8; i++) {
    if (be[i] >= 0) {
      int p = lbase_e[be[i]] + atomicAdd(&lcnt_e[be[i]], 1);
      if (p < BKCAP) bk[(size_t)be[i] * BKCAP + p] = pe[i];
      p = lbase_n[bn[i]] + atomicAdd(&lcnt_n[bn[i]], 1);
      if (p < BKCAP) bk[(size_t)(NBK + bn[i]) * BKCAP + p] = pn[i];
    }
  }
}

// ===== K2: per-bucket counting sort -> off[] + col[]; scatter stays in hot L2 =====
__global__ __launch_bounds__(512) void bucket_sort_kernel(const int* __restrict__ gcnt,
                                                          const unsigned* __restrict__ bk,
                                                          int* __restrict__ off_e, int* __restrict__ off_v,
                                                          int* __restrict__ col_e, int* __restrict__ col_v) {
  const int gb = blockIdx.x;                       // 0..2*NBK-1
  const int dir = gb >= NBK ? 1 : 0;
  const int b = dir ? gb - NBK : gb;
  const int* __restrict__ cnt = gcnt + dir * NBK;
  const unsigned* __restrict__ bkd = bk + ((size_t)dir * NBK + b) * BKCAP;
  int* __restrict__ off = dir ? off_v : off_e;
  int* __restrict__ col = dir ? col_v : col_e;
  const int tid = threadIdx.x, lane = tid & 63, wid = tid >> 6;
  __shared__ int lcnt[512];
  __shared__ int wsum[8];
  __shared__ int base_s;
  if (tid < 64) {                                   // base = sum cnt[0..b)
    int s = 0;
    for (int t = tid; t < b; t += 64) s += cnt[t];
    #pragma unroll
    for (int d = 1; d < 64; d <<= 1) s += __shfl_xor(s, d);
    if (tid == 0) base_s = s;
  }
  lcnt[tid] = 0;
  __syncthreads();
  const int n = min(cnt[b], BKCAP);
  for (int i = tid; i < n; i += 512)
    atomicAdd(&lcnt[bkd[i] >> 17], 1);
  __syncthreads();
  int x = lcnt[tid];                                // per-row count
  int inc = x;
  #pragma unroll
  for (int d = 1; d < 64; d <<= 1) { int t = __shfl_up(inc, d); if (lane >= d) inc += t; }
  if (lane == 63) wsum[wid] = inc;
  __syncthreads();
  int wbase = 0;
  for (int k = 0; k < wid; k++) wbase += wsum[k];
  const int gpos = base_s + wbase + inc - x;        // global exclusive position for row tid
  const int row = (b << 9) + tid;
  if (row < NODES) off[row] = gpos;
  if (b == NBK - 1 && tid == 0) off[NODES] = NNZV;
  __syncthreads();
  lcnt[tid] = gpos;                                 // cursor = global position
  __syncthreads();
  for (int i = tid; i < n; i += 512) {
    unsigned e = bkd[i];
    int p = atomicAdd(&lcnt[e >> 17], 1);
    col[p] = (int)(e & 0x1FFFFu);
  }
}

// ======= MFMA GEMM: Y(slice-major, OS feats/slice) = X[M,128] @ W[128,N] =======
// XBF=0: X is f32 row-major. XBF=1: X is bf16 slice-major [8][NR][16].
template<int N, bool XBF, int OS>
__global__ __launch_bounds__(256) void gemm_kernel(const void* __restrict__ Xv,
                                                   const u16* __restrict__ WT,
                                                   u16* __restrict__ Y, int M) {
  __shared__ u16 sX[64 * 136];
  __shared__ u16 sW[N * 136];
  const int tid = threadIdx.x, lane = tid & 63, w = tid >> 6;
  const int chunk = blockIdx.x * 64;
  constexpr int WV = N * 128 / 8;
  for (int t = tid; t < WV; t += 256) {
    int e = t * 8, n = e >> 7, k = e & 127;
    *(bf16x8*)(sW + n * 136 + k) = *(const bf16x8*)(WT + n * 128 + k);
  }
  if constexpr (XBF) {
    const u16* X = (const u16*)Xv;                  // slice-major [8][NR][16]
    for (int t = tid; t < 1024; t += 256) {
      int ss = t >> 7;                              // slice
      int u = t & 127;
      int r = u >> 1, half = u & 1;
      int row = min(chunk + r, M - 1);
      *(bf16x8*)(sX + r * 136 + ss * 16 + half * 8) =
          *(const bf16x8*)(X + (size_t)ss * NR * 16 + (size_t)row * 16 + half * 8);
    }
  } else {
    const float* X = (const float*)Xv;
    for (int t = tid; t < 2048; t += 256) {
      int r = t >> 5, c4 = t & 31;
      int row = min(chunk + r, M - 1);
      float4 v = *(const float4*)(X + (size_t)row * 128 + c4 * 4);
      ushort4 o = { f2b(v.x), f2b(v.y), f2b(v.z), f2b(v.w) };
      *(ushort4*)(sX + r * 136 + c4 * 4) = o;
    }
  }
  __syncthreads();
  constexpr int CW = N / 2;
  constexpr int NT = CW / 16;
  const int wr = w >> 1, wc = w & 1;
  const int l15 = lane & 15;
  const int arow = wr * 32 + l15;
  const int kb = (lane >> 4) * 8;
  f32x4 acc[2][NT];
  #pragma unroll
  for (int rt = 0; rt < 2; rt++)
    #pragma unroll
    for (int nt = 0; nt < NT; nt++) acc[rt][nt] = (f32x4){0.f, 0.f, 0.f, 0.f};
  #pragma unroll
  for (int kk = 0; kk < 4; kk++) {
    const int ko = kk * 32 + kb;
    bf16x8 a0 = *(const bf16x8*)(sX + arow * 136 + ko);
    bf16x8 a1 = *(const bf16x8*)(sX + (arow + 16) * 136 + ko);
    #pragma unroll
    for (int nt = 0; nt < NT; nt++) {
      bf16x8 bb = *(const bf16x8*)(sW + (wc * CW + nt * 16 + l15) * 136 + ko);
      acc[0][nt] = __builtin_amdgcn_mfma_f32_16x16x32_bf16(a0, bb, acc[0][nt], 0, 0, 0);
      acc[1][nt] = __builtin_amdgcn_mfma_f32_16x16x32_bf16(a1, bb, acc[1][nt], 0, 0, 0);
    }
  }
  const int r4 = (lane >> 4) * 4;
  #pragma unroll
  for (int rt = 0; rt < 2; rt++)
    #pragma unroll
    for (int r = 0; r < 4; r++) {
      int row = chunk + wr * 32 + rt * 16 + r4 + r;
      if (row < M) {
        #pragma unroll
        for (int nt = 0; nt < NT; nt++) {
          int cn = wc * CW + nt * 16 + l15;
          int sl = cn / OS, fi = cn % OS;
          Y[(size_t)sl * NR * OS + (size_t)row * OS + fi] = f2b(acc[rt][nt][r]);
        }
      }
    }
}

// ===== pipelined XCD-sliced gather: group s (blockIdx%8 -> XCD s), slice s, all rows =====
// Wave = 8 rows x 8 lanes; per row SLOTS member-slots x LPM lanes; one loop iteration
// issues 4 independent batches (4 cached col reads + 4 independent 16B src loads),
// then predicated accumulates. Clamped out-of-range loads coalesce (same address).
// src slice-major [8][NR][SLICE] bf16; dst bf16 slice-major or f32 row-major (F32OUT).
template<int F, bool HASB, bool RELU, bool F32OUT>
__global__ __launch_bounds__(256) void gatherS_kernel(const int* __restrict__ off,
                                                      const int* __restrict__ col,
                                                      const u16* __restrict__ src,
                                                      const float* __restrict__ bias,
                                                      void* __restrict__ dstv, int nrows) {
  constexpr int SLICE = F / 8;              // feats per slice: 16 or 8
  constexpr int LPM   = SLICE / 8;          // lanes per member: 2 or 1
  constexpr int SLOTS = 8 / LPM;            // member slots per row: 4 or 8
  const int s = blockIdx.x & 7;             // slice / XCD group
  const int b = blockIdx.x >> 3;
  const int lane = threadIdx.x & 63, wave = threadIdx.x >> 6;
  const int r = lane >> 3;                  // row within wave (0..7)
  const int p = lane & 7;
  const int slot = p / LPM;
  const int l = p % LPM;                    // 8-feat block within slice
  const u16* __restrict__ srcS = src + (size_t)s * NR * SLICE;
  float bi[8];
  if constexpr (HASB) {
    #pragma unroll
    for (int t = 0; t < 8; t++) bi[t] = bias[s * SLICE + l * 8 + t];
  }
  for (int row0 = b * 32 + wave * 8; row0 < nrows; row0 += NBGS * 32) {
    const int row = row0 + r;
    const bool act = row < nrows;
    const int s0 = act ? off[row] : 0;
    const int s1 = act ? off[row + 1] : 0;
    float acc[8] = {};
    for (int k = s0; k < s1; k += 4 * SLOTS) {   // one iter = 4 batches in flight
      const int i0 = k + slot;
      const int i1 = i0 + SLOTS;
      const int i2 = i1 + SLOTS;
      const int i3 = i2 + SLOTS;
      const int c0 = col[min(i0, s1 - 1)];
      const int c1 = col[min(i1, s1 - 1)];
      const int c2 = col[min(i2, s1 - 1)];
      const int c3 = col[min(i3, s1 - 1)];
      bf16x8 v0 = *(const bf16x8*)(srcS + (size_t)c0 * SLICE + l * 8);
      bf16x8 v1 = *(const bf16x8*)(srcS + (size_t)c1 * SLICE + l * 8);
      bf16x8 v2 = *(const bf16x8*)(srcS + (size_t)c2 * SLICE + l * 8);
      bf16x8 v3 = *(const bf16x8*)(srcS + (size_t)c3 * SLICE + l * 8);
      if (i0 < s1) {
        #pragma unroll
        for (int t = 0; t < 8; t++) acc[t] += b2f((u16)v0[t]);
      }
      if (i1 < s1) {
        #pragma unroll
        for (int t = 0; t < 8; t++) acc[t] += b2f((u16)v1[t]);
      }
      if (i2 < s1) {
        #pragma unroll
        for (int t = 0; t < 8; t++) acc[t] += b2f((u16)v2[t]);
      }
      if (i3 < s1) {
        #pragma unroll
        for (int t = 0; t < 8; t++) acc[t] += b2f((u16)v3[t]);
      }
    }
    // reduce across slots (xor within the 8-lane row group; preserves l and r)
    #pragma unroll
    for (int d = LPM; d < 8; d <<= 1)
      #pragma unroll
      for (int t = 0; t < 8; t++) acc[t] += __shfl_xor(acc[t], d);
    if (slot == 0 && act) {
      const float sc = (s1 > s0) ? 1.0f / (float)(s1 - s0) : 0.f;
      float v[8];
      #pragma unroll
      for (int t = 0; t < 8; t++) {
        v[t] = acc[t] * sc;
        if constexpr (HASB) v[t] += bi[t];
        if constexpr (RELU) v[t] = fmaxf(v[t], 0.f);
      }
      if constexpr (F32OUT) {
        float* d = (float*)dstv + (size_t)row * 64 + s * 8 + l * 8;
        f32x4 o0 = {v[0], v[1], v[2], v[3]};
        f32x4 o1 = {v[4], v[5], v[6], v[7]};
        __builtin_nontemporal_store(o0, (f32x4*)d);
        __builtin_nontemporal_store(o1, (f32x4*)(d + 4));
      } else {
        bf16x8 o;
        #pragma unroll
        for (int t = 0; t < 8; t++) o[t] = (short)f2b(v[t]);
        __builtin_nontemporal_store(
            o, (bf16x8*)((u16*)dstv + (size_t)s * NR * SLICE + (size_t)row * SLICE + l * 8));
      }
    }
  }
}

extern "C" void kernel_launch(void* const* d_in, const int* in_sizes, int n_in,
                              void* d_out, int out_size, void* d_ws, size_t ws_size,
                              hipStream_t stream) {
  const float* x  = (const float*)d_in[0];
  const int*   hi = (const int*)d_in[1];
  const float* W1 = (const float*)d_in[2];
  const float* b1 = (const float*)d_in[3];
  const float* W2 = (const float*)d_in[4];
  const float* b2 = (const float*)d_in[5];
  float* out = (float*)d_out;
  const int* nidx = hi;             // row 0: node indices
  const int* eidx = hi + NNZV;      // row 1: edge indices

  char* w = (char*)d_ws;
  int*      off_e = (int*)w;                           // 100001 ints
  int*      off_v = (int*)(w + 524288);                // 100001 ints
  int*      gcnt  = (int*)(w + 1048576);               // 392 ints
  u16*      W1T   = (u16*)(w + 1052672);               // 128x128 bf16
  u16*      W2T   = (u16*)(w + 1085440);               // 64x128 bf16
  int*      col_e = (int*)(w + 2097152);               // 1.6M ints
  int*      col_v = (int*)(w + 8650752);               // 1.6M ints
  unsigned* bk    = (unsigned*)(w + 16777216);         // 19.3 MB
  u16*      bufH  = (u16*)(w + 56623104);              // 25.6 MB: h1 / h2 / m2e (slice-major)
  u16*      bufM  = (u16*)(w + 56623104 + 25600000);   // 25.6 MB: m_e / g2 (slice-major)

  // ---- weight pre-transpose + CSR build ----
  hipMemsetAsync(gcnt, 0, 392 * 4, stream);
  wtrans_kernel<<<96, 256, 0, stream>>>(W1, W2, W1T, W2T);
  partition_kernel<<<NTIL2, 256, 0, stream>>>(nidx, eidx, gcnt, bk);
  bucket_sort_kernel<<<2 * NBK, 512, 0, stream>>>(gcnt, bk, off_e, off_v, col_e, col_v);

  // ---- conv1 (F=128, slice-major SLICE=16) ----
  gemm_kernel<128, false, 16><<<1563, 256, 0, stream>>>(x, W1T, bufH, NODES);      // h1
  gatherS_kernel<128, false, false, false><<<8 * NBGS, 256, 0, stream>>>(
      off_e, col_e, bufH, nullptr, bufM, EDGES);                                   // m_e
  gatherS_kernel<128, true, true, false><<<8 * NBGS, 256, 0, stream>>>(
      off_v, col_v, bufM, b1, bufH, NODES);                                        // h2
  // ---- conv2 (F=64, slice-major SLICE=8) ----
  gemm_kernel<64, true, 8><<<1563, 256, 0, stream>>>(bufH, W2T, bufM, NODES);      // g2
  gatherS_kernel<64, false, false, false><<<8 * NBGS, 256, 0, stream>>>(
      off_e, col_e, bufM, nullptr, bufH, EDGES);                                   // m2e
  gatherS_kernel<64, true, false, true><<<8 * NBGS, 256, 0, stream>>>(
      off_v, col_v, bufH, b2, out, NODES);                                         // out(f32)
}

// Round 13
// 290.083 us; speedup vs baseline: 2.9377x; 1.3285x over previous
//
#include <hip/hip_runtime.h>

#define NODES 100000
#define EDGES 100000
#define NNZV  1600000
#define NBK   196          // buckets per direction (512 rows each)
#define BKCAP 12288        // entry capacity per bucket (mean 8192)
#define TILE2 2048         // entries per partition block (256 thr x 8, both dirs)
#define NTIL2 782          // ceil(NNZV / TILE2)

typedef unsigned short u16;
typedef __attribute__((ext_vector_type(8))) short bf16x8;   // 8 bf16 (4 VGPRs)
typedef __attribute__((ext_vector_type(4))) float f32x4;

__device__ __forceinline__ float b2f(u16 h) {
  union { unsigned u; float f; } c; c.u = ((unsigned)h) << 16; return c.f;
}
__device__ __forceinline__ u16 f2b(float f) {
  union { unsigned u; float f; } c; c.f = f;
  unsigned u = c.u + 0x7FFF + ((c.u >> 16) & 1);   // round-to-nearest-even
  return (u16)(u >> 16);
}

// ============ W pre-transpose: W1T[n][128] = bf16(W1[k][n]), same for W2 ============
__global__ __launch_bounds__(256) void wtrans_kernel(const float* __restrict__ W1,
                                                     const float* __restrict__ W2,
                                                     u16* __restrict__ W1T, u16* __restrict__ W2T) {
  int i = blockIdx.x * 256 + threadIdx.x;
  if (i < 16384) {
    int k = i >> 7, n = i & 127;
    W1T[n * 128 + k] = f2b(W1[i]);
  } else if (i < 16384 + 8192) {
    int j = i - 16384;
    int k = j >> 6, n = j & 63;
    W2T[n * 128 + k] = f2b(W2[j]);
  }
}

// ====== K1: single-pass dual-direction partition into 2x196 row-range buckets ======
__global__ __launch_bounds__(256) void partition_kernel(const int* __restrict__ nidx,
                                                        const int* __restrict__ eidx,
                                                        int* __restrict__ gcnt,
                                                        unsigned* __restrict__ bk) {
  __shared__ int lcnt_e[NBK], lcnt_n[NBK], lbase_e[NBK], lbase_n[NBK];
  const int tid = threadIdx.x;
  const int j0 = blockIdx.x * TILE2;
  for (int i = tid; i < NBK; i += 256) { lcnt_e[i] = 0; lcnt_n[i] = 0; }
  __syncthreads();
  int be[8], bn[8]; unsigned pe[8], pn[8];
  #pragma unroll
  for (int i = 0; i < 8; i++) {
    int j = j0 + tid + i * 256;
    if (j < NNZV) {
      int e = __builtin_nontemporal_load(eidx + j);
      int n = __builtin_nontemporal_load(nidx + j);
      be[i] = e >> 9; pe[i] = ((unsigned)(e & 511) << 17) | (unsigned)n;
      bn[i] = n >> 9; pn[i] = ((unsigned)(n & 511) << 17) | (unsigned)e;
      atomicAdd(&lcnt_e[be[i]], 1);
      atomicAdd(&lcnt_n[bn[i]], 1);
    } else { be[i] = -1; bn[i] = -1; }
  }
  __syncthreads();
  for (int b = tid; b < NBK; b += 256) {
    int c = lcnt_e[b];
    lbase_e[b] = c ? atomicAdd(&gcnt[b], c) : 0;
    lcnt_e[b] = 0;
    c = lcnt_n[b];
    lbase_n[b] = c ? atomicAdd(&gcnt[NBK + b], c) : 0;
    lcnt_n[b] = 0;
  }
  __syncthreads();
  #pragma unroll
  for (int i = 0; i < 8; i++) {
    if (be[i] >= 0) {
      int p = lbase_e[be[i]] + atomicAdd(&lcnt_e[be[i]], 1);
      if (p < BKCAP) bk[(size_t)be[i] * BKCAP + p] = pe[i];
      p = lbase_n[bn[i]] + atomicAdd(&lcnt_n[bn[i]], 1);
      if (p < BKCAP) bk[(size_t)(NBK + bn[i]) * BKCAP + p] = pn[i];
    }
  }
}

// ===== K2: per-bucket counting sort -> off[] + col[]; scatter stays in hot L2 =====
__global__ __launch_bounds__(512) void bucket_sort_kernel(const int* __restrict__ gcnt,
                                                          const unsigned* __restrict__ bk,
                                                          int* __restrict__ off_e, int* __restrict__ off_v,
                                                          int* __restrict__ col_e, int* __restrict__ col_v) {
  const int gb = blockIdx.x;                       // 0..2*NBK-1
  const int dir = gb >= NBK ? 1 : 0;
  const int b = dir ? gb - NBK : gb;
  const int* __restrict__ cnt = gcnt + dir * NBK;
  const unsigned* __restrict__ bkd = bk + ((size_t)dir * NBK + b) * BKCAP;
  int* __restrict__ off = dir ? off_v : off_e;
  int* __restrict__ col = dir ? col_v : col_e;
  const int tid = threadIdx.x, lane = tid & 63, wid = tid >> 6;
  __shared__ int lcnt[512];
  __shared__ int wsum[8];
  __shared__ int base_s;
  if (tid < 64) {                                   // base = sum cnt[0..b)
    int s = 0;
    for (int t = tid; t < b; t += 64) s += cnt[t];
    #pragma unroll
    for (int d = 1; d < 64; d <<= 1) s += __shfl_xor(s, d);
    if (tid == 0) base_s = s;
  }
  lcnt[tid] = 0;
  __syncthreads();
  const int n = min(cnt[b], BKCAP);
  for (int i = tid; i < n; i += 512)
    atomicAdd(&lcnt[bkd[i] >> 17], 1);
  __syncthreads();
  int x = lcnt[tid];                                // per-row count
  int inc = x;
  #pragma unroll
  for (int d = 1; d < 64; d <<= 1) { int t = __shfl_up(inc, d); if (lane >= d) inc += t; }
  if (lane == 63) wsum[wid] = inc;
  __syncthreads();
  int wbase = 0;
  for (int k = 0; k < wid; k++) wbase += wsum[k];
  const int gpos = base_s + wbase + inc - x;        // global exclusive position for row tid
  const int row = (b << 9) + tid;
  if (row < NODES) off[row] = gpos;
  if (b == NBK - 1 && tid == 0) off[NODES] = NNZV;
  __syncthreads();
  lcnt[tid] = gpos;                                 // cursor = global position
  __syncthreads();
  for (int i = tid; i < n; i += 512) {
    unsigned e = bkd[i];
    int p = atomicAdd(&lcnt[e >> 17], 1);
    col[p] = (int)(e & 0x1FFFFu);
  }
}

// ======= MFMA GEMM: Y[M,N](bf16) = X[M,128] @ W[128,N]; WT is pre-transposed bf16 [N][128] =======
template<int N, bool XBF>
__global__ __launch_bounds__(256) void gemm_kernel(const void* __restrict__ Xv,
                                                   const u16* __restrict__ WT,
                                                   u16* __restrict__ Y, int M) {
  __shared__ u16 sX[64 * 136];
  __shared__ u16 sW[N * 136];
  const int tid = threadIdx.x, lane = tid & 63, w = tid >> 6;
  const int chunk = blockIdx.x * 64;
  constexpr int WV = N * 128 / 8;
  for (int t = tid; t < WV; t += 256) {
    int e = t * 8, n = e >> 7, k = e & 127;
    *(bf16x8*)(sW + n * 136 + k) = *(const bf16x8*)(WT + n * 128 + k);
  }
  if constexpr (XBF) {
    const u16* X = (const u16*)Xv;
    for (int t = tid; t < 1024; t += 256) {
      int e = t * 8, r = e >> 7, k = e & 127;
      int row = min(chunk + r, M - 1);
      *(bf16x8*)(sX + r * 136 + k) = *(const bf16x8*)(X + (size_t)row * 128 + k);
    }
  } else {
    const float* X = (const float*)Xv;
    for (int t = tid; t < 2048; t += 256) {
      int r = t >> 5, c4 = t & 31;
      int row = min(chunk + r, M - 1);
      float4 v = *(const float4*)(X + (size_t)row * 128 + c4 * 4);
      ushort4 o = { f2b(v.x), f2b(v.y), f2b(v.z), f2b(v.w) };
      *(ushort4*)(sX + r * 136 + c4 * 4) = o;
    }
  }
  __syncthreads();
  constexpr int CW = N / 2;
  constexpr int NT = CW / 16;
  const int wr = w >> 1, wc = w & 1;
  const int l15 = lane & 15;
  const int arow = wr * 32 + l15;
  const int kb = (lane >> 4) * 8;
  f32x4 acc[2][NT];
  #pragma unroll
  for (int rt = 0; rt < 2; rt++)
    #pragma unroll
    for (int nt = 0; nt < NT; nt++) acc[rt][nt] = (f32x4){0.f, 0.f, 0.f, 0.f};
  #pragma unroll
  for (int kk = 0; kk < 4; kk++) {
    const int ko = kk * 32 + kb;
    bf16x8 a0 = *(const bf16x8*)(sX + arow * 136 + ko);
    bf16x8 a1 = *(const bf16x8*)(sX + (arow + 16) * 136 + ko);
    #pragma unroll
    for (int nt = 0; nt < NT; nt++) {
      bf16x8 bb = *(const bf16x8*)(sW + (wc * CW + nt * 16 + l15) * 136 + ko);
      acc[0][nt] = __builtin_amdgcn_mfma_f32_16x16x32_bf16(a0, bb, acc[0][nt], 0, 0, 0);
      acc[1][nt] = __builtin_amdgcn_mfma_f32_16x16x32_bf16(a1, bb, acc[1][nt], 0, 0, 0);
    }
  }
  const int r4 = (lane >> 4) * 4;
  #pragma unroll
  for (int rt = 0; rt < 2; rt++)
    #pragma unroll
    for (int r = 0; r < 4; r++) {
      int row = chunk + wr * 32 + rt * 16 + r4 + r;
      if (row < M) {
        #pragma unroll
        for (int nt = 0; nt < NT; nt++)
          Y[(size_t)row * N + wc * CW + nt * 16 + l15] = f2b(acc[rt][nt][r]);
      }
    }
}

// ===== F=128 member-parallel gather (R8 structure, verbatim): wave = 1 row =====
// lane = (member-slot g of 4, 16B feature-block l of 16); one VMEM = 4 member sub-rows.
template<bool HASB, bool RELU>
__global__ __launch_bounds__(256) void gather128_kernel(const int* __restrict__ off,
                                                        const int* __restrict__ col,
                                                        const u16* __restrict__ src,
                                                        const float* __restrict__ bias,
                                                        u16* __restrict__ dst, int nrows) {
  constexpr int G = 4, L = 16;
  const int row = blockIdx.x * 4 + (threadIdx.x >> 6);
  if (row >= nrows) return;
  const int lane = threadIdx.x & 63;
  const int g = lane / L;
  const int l = lane % L;
  const int s0 = off[row], s1 = off[row + 1];
  float acc[8] = {};
  int k = s0;
  for (; k + 4 * G <= s1; k += 4 * G) {
    int c0 = col[k + g];
    int c1 = col[k + G + g];
    int c2 = col[k + 2 * G + g];
    int c3 = col[k + 3 * G + g];
    bf16x8 v0 = *(const bf16x8*)(src + (size_t)c0 * 128 + l * 8);
    bf16x8 v1 = *(const bf16x8*)(src + (size_t)c1 * 128 + l * 8);
    bf16x8 v2 = *(const bf16x8*)(src + (size_t)c2 * 128 + l * 8);
    bf16x8 v3 = *(const bf16x8*)(src + (size_t)c3 * 128 + l * 8);
    #pragma unroll
    for (int t = 0; t < 8; t++) acc[t] += b2f((u16)v0[t]);
    #pragma unroll
    for (int t = 0; t < 8; t++) acc[t] += b2f((u16)v1[t]);
    #pragma unroll
    for (int t = 0; t < 8; t++) acc[t] += b2f((u16)v2[t]);
    #pragma unroll
    for (int t = 0; t < 8; t++) acc[t] += b2f((u16)v3[t]);
  }
  for (; k < s1; k += G) {
    int idx = k + g;
    int c = col[min(idx, s1 - 1)];
    bf16x8 v = *(const bf16x8*)(src + (size_t)c * 128 + l * 8);
    if (idx < s1) {
      #pragma unroll
      for (int t = 0; t < 8; t++) acc[t] += b2f((u16)v[t]);
    }
  }
  #pragma unroll
  for (int d = L; d < 64; d <<= 1) {
    #pragma unroll
    for (int t = 0; t < 8; t++) acc[t] += __shfl_xor(acc[t], d);
  }
  if (g == 0) {
    const float sc = (s1 > s0) ? 1.0f / (float)(s1 - s0) : 0.f;
    float v[8];
    #pragma unroll
    for (int t = 0; t < 8; t++) {
      v[t] = acc[t] * sc;
      if constexpr (HASB) v[t] += bias[l * 8 + t];
      if constexpr (RELU) v[t] = fmaxf(v[t], 0.f);
    }
    bf16x8 o;
    #pragma unroll
    for (int t = 0; t < 8; t++) o[t] = (short)f2b(v[t]);
    *(bf16x8*)(dst + (size_t)row * 128 + l * 8) = o;
  }
}

// ===== F=64 gather, 2 rows per wave: halves wave-visit count vs R8 =====
// lane: rr = row half (0/1), g = member slot (4), l = 16B feat block (8 -> 64 feats).
template<bool HASB, bool F32OUT>
__global__ __launch_bounds__(256) void gather64_kernel(const int* __restrict__ off,
                                                       const int* __restrict__ col,
                                                       const u16* __restrict__ src,
                                                       const float* __restrict__ bias,
                                                       void* __restrict__ dstv, int nrows) {
  const int lane = threadIdx.x & 63, wave = threadIdx.x >> 6;
  const int rr = lane >> 5;
  const int lr = lane & 31;
  const int g = lr >> 3;                  // member slot 0..3
  const int l = lr & 7;                   // 8-feat block
  const int row = blockIdx.x * 8 + wave * 2 + rr;
  const bool act = row < nrows;
  const int s0 = act ? off[row] : 0;
  const int s1 = act ? off[row + 1] : 0;
  float acc[8] = {};
  for (int k = s0; k < s1; k += 16) {     // 4 batches of 4 members in flight
    const int i0 = k + g, i1 = i0 + 4, i2 = i0 + 8, i3 = i0 + 12;
    const int c0 = col[min(i0, s1 - 1)];
    const int c1 = col[min(i1, s1 - 1)];
    const int c2 = col[min(i2, s1 - 1)];
    const int c3 = col[min(i3, s1 - 1)];
    bf16x8 v0 = *(const bf16x8*)(src + (size_t)c0 * 64 + l * 8);
    bf16x8 v1 = *(const bf16x8*)(src + (size_t)c1 * 64 + l * 8);
    bf16x8 v2 = *(const bf16x8*)(src + (size_t)c2 * 64 + l * 8);
    bf16x8 v3 = *(const bf16x8*)(src + (size_t)c3 * 64 + l * 8);
    if (i0 < s1) {
      #pragma unroll
      for (int t = 0; t < 8; t++) acc[t] += b2f((u16)v0[t]);
    }
    if (i1 < s1) {
      #pragma unroll
      for (int t = 0; t < 8; t++) acc[t] += b2f((u16)v1[t]);
    }
    if (i2 < s1) {
      #pragma unroll
      for (int t = 0; t < 8; t++) acc[t] += b2f((u16)v2[t]);
    }
    if (i3 < s1) {
      #pragma unroll
      for (int t = 0; t < 8; t++) acc[t] += b2f((u16)v3[t]);
    }
  }
  // reduce across the 4 member slots (xor d=8,16 stays within the 32-lane row group)
  #pragma unroll
  for (int d = 8; d < 32; d <<= 1) {
    #pragma unroll
    for (int t = 0; t < 8; t++) acc[t] += __shfl_xor(acc[t], d);
  }
  if (g == 0 && act) {
    const float sc = (s1 > s0) ? 1.0f / (float)(s1 - s0) : 0.f;
    float v[8];
    #pragma unroll
    for (int t = 0; t < 8; t++) {
      v[t] = acc[t] * sc;
      if constexpr (HASB) v[t] += bias[l * 8 + t];
    }
    if constexpr (F32OUT) {
      float* d = (float*)dstv + (size_t)row * 64 + l * 8;
      *(float4*)d = make_float4(v[0], v[1], v[2], v[3]);
      *(float4*)(d + 4) = make_float4(v[4], v[5], v[6], v[7]);
    } else {
      bf16x8 o;
      #pragma unroll
      for (int t = 0; t < 8; t++) o[t] = (short)f2b(v[t]);
      *(bf16x8*)((u16*)dstv + (size_t)row * 64 + l * 8) = o;
    }
  }
}

extern "C" void kernel_launch(void* const* d_in, const int* in_sizes, int n_in,
                              void* d_out, int out_size, void* d_ws, size_t ws_size,
                              hipStream_t stream) {
  const float* x  = (const float*)d_in[0];
  const int*   hi = (const int*)d_in[1];
  const float* W1 = (const float*)d_in[2];
  const float* b1 = (const float*)d_in[3];
  const float* W2 = (const float*)d_in[4];
  const float* b2 = (const float*)d_in[5];
  float* out = (float*)d_out;
  const int* nidx = hi;             // row 0: node indices
  const int* eidx = hi + NNZV;      // row 1: edge indices

  char* w = (char*)d_ws;
  int*      off_e = (int*)w;                           // 100001 ints
  int*      off_v = (int*)(w + 524288);                // 100001 ints
  int*      gcnt  = (int*)(w + 1048576);               // 392 ints
  u16*      W1T   = (u16*)(w + 1052672);               // 128x128 bf16
  u16*      W2T   = (u16*)(w + 1085440);               // 64x128 bf16
  int*      col_e = (int*)(w + 2097152);               // 1.6M ints
  int*      col_v = (int*)(w + 8650752);               // 1.6M ints
  unsigned* bk    = (unsigned*)(w + 16777216);         // 2*196*12288*4B = 19.3 MB
  u16*      bufH  = (u16*)(w + 56623104);              // 25.6 MB: h1, then h2, then m2e
  u16*      bufM  = (u16*)(w + 56623104 + 25600000);   // 25.6 MB: m_e, then g2

  // ---- weight pre-transpose + CSR build ----
  hipMemsetAsync(gcnt, 0, 392 * 4, stream);
  wtrans_kernel<<<96, 256, 0, stream>>>(W1, W2, W1T, W2T);
  partition_kernel<<<NTIL2, 256, 0, stream>>>(nidx, eidx, gcnt, bk);
  bucket_sort_kernel<<<2 * NBK, 512, 0, stream>>>(gcnt, bk, off_e, off_v, col_e, col_v);

  // ---- conv1 (F=128) ----
  gemm_kernel<128, false><<<1563, 256, 0, stream>>>(x, W1T, bufH, NODES);          // h1(bf16)
  gather128_kernel<false, false><<<(EDGES + 3) / 4, 256, 0, stream>>>(
      off_e, col_e, bufH, nullptr, bufM, EDGES);                                   // m_e
  gather128_kernel<true, true><<<(NODES + 3) / 4, 256, 0, stream>>>(
      off_v, col_v, bufM, b1, bufH, NODES);                                        // h2
  // ---- conv2 (F=64) ----
  gemm_kernel<64, true><<<1563, 256, 0, stream>>>(bufH, W2T, bufM, NODES);         // g2(bf16)
  gather64_kernel<false, false><<<(EDGES + 7) / 8, 256, 0, stream>>>(
      off_e, col_e, bufM, nullptr, bufH, EDGES);                                   // m2e
  gather64_kernel<true, true><<<(NODES + 7) / 8, 256, 0, stream>>>(
      off_v, col_v, bufH, b2, out, NODES);                                         // out(f32)
}

// Round 14
// 279.931 us; speedup vs baseline: 3.0442x; 1.0363x over previous
//
#include <hip/hip_runtime.h>

#define NODES 100000
#define EDGES 100000
#define NNZV  1600000
#define NBK   196          // buckets per direction (512 rows each)
#define BKCAP 12288        // entry capacity per bucket (mean 8192)
#define TILE2 4096         // entries per partition block (256 thr x 16, both dirs)
#define NTIL2 391          // ceil(NNZV / TILE2)

typedef unsigned short u16;
typedef __attribute__((ext_vector_type(8))) short bf16x8;   // 8 bf16 (4 VGPRs)
typedef __attribute__((ext_vector_type(4))) float f32x4;

__device__ __forceinline__ float b2f(u16 h) {
  union { unsigned u; float f; } c; c.u = ((unsigned)h) << 16; return c.f;
}
__device__ __forceinline__ u16 f2b(float f) {
  union { unsigned u; float f; } c; c.f = f;
  unsigned u = c.u + 0x7FFF + ((c.u >> 16) & 1);   // round-to-nearest-even
  return (u16)(u >> 16);
}

// ============ W pre-transpose: W1T[n][128] = bf16(W1[k][n]), same for W2 ============
__global__ __launch_bounds__(256) void wtrans_kernel(const float* __restrict__ W1,
                                                     const float* __restrict__ W2,
                                                     u16* __restrict__ W1T, u16* __restrict__ W2T) {
  int i = blockIdx.x * 256 + threadIdx.x;
  if (i < 16384) {
    int k = i >> 7, n = i & 127;
    W1T[n * 128 + k] = f2b(W1[i]);
  } else if (i < 16384 + 8192) {
    int j = i - 16384;
    int k = j >> 6, n = j & 63;
    W2T[n * 128 + k] = f2b(W2[j]);
  }
}

// ====== K1: single-pass dual-direction partition into 2x196 row-range buckets ======
__global__ __launch_bounds__(256) void partition_kernel(const int* __restrict__ nidx,
                                                        const int* __restrict__ eidx,
                                                        int* __restrict__ gcnt,
                                                        unsigned* __restrict__ bk) {
  __shared__ int lcnt_e[NBK], lcnt_n[NBK], lbase_e[NBK], lbase_n[NBK];
  const int tid = threadIdx.x;
  const int j0 = blockIdx.x * TILE2;
  for (int i = tid; i < NBK; i += 256) { lcnt_e[i] = 0; lcnt_n[i] = 0; }
  __syncthreads();
  int be[16], bn[16]; unsigned pe[16], pn[16];
  #pragma unroll
  for (int i = 0; i < 16; i++) {
    int j = j0 + tid + i * 256;
    if (j < NNZV) {
      int e = __builtin_nontemporal_load(eidx + j);
      int n = __builtin_nontemporal_load(nidx + j);
      be[i] = e >> 9; pe[i] = ((unsigned)(e & 511) << 17) | (unsigned)n;
      bn[i] = n >> 9; pn[i] = ((unsigned)(n & 511) << 17) | (unsigned)e;
      atomicAdd(&lcnt_e[be[i]], 1);
      atomicAdd(&lcnt_n[bn[i]], 1);
    } else { be[i] = -1; bn[i] = -1; }
  }
  __syncthreads();
  for (int b = tid; b < NBK; b += 256) {
    int c = lcnt_e[b];
    lbase_e[b] = c ? atomicAdd(&gcnt[b], c) : 0;
    lcnt_e[b] = 0;
    c = lcnt_n[b];
    lbase_n[b] = c ? atomicAdd(&gcnt[NBK + b], c) : 0;
    lcnt_n[b] = 0;
  }
  __syncthreads();
  #pragma unroll
  for (int i = 0; i < 16; i++) {
    if (be[i] >= 0) {
      int p = lbase_e[be[i]] + atomicAdd(&lcnt_e[be[i]], 1);
      if (p < BKCAP) bk[(size_t)be[i] * BKCAP + p] = pe[i];
      p = lbase_n[bn[i]] + atomicAdd(&lcnt_n[bn[i]], 1);
      if (p < BKCAP) bk[(size_t)(NBK + bn[i]) * BKCAP + p] = pn[i];
    }
  }
}

// ===== K2: per-bucket counting sort -> off[] + col[]; scatter stays in hot L2 =====
__global__ __launch_bounds__(512) void bucket_sort_kernel(const int* __restrict__ gcnt,
                                                          const unsigned* __restrict__ bk,
                                                          int* __restrict__ off_e, int* __restrict__ off_v,
                                                          int* __restrict__ col_e, int* __restrict__ col_v) {
  const int gb = blockIdx.x;                       // 0..2*NBK-1
  const int dir = gb >= NBK ? 1 : 0;
  const int b = dir ? gb - NBK : gb;
  const int* __restrict__ cnt = gcnt + dir * NBK;
  const unsigned* __restrict__ bkd = bk + ((size_t)dir * NBK + b) * BKCAP;
  int* __restrict__ off = dir ? off_v : off_e;
  int* __restrict__ col = dir ? col_v : col_e;
  const int tid = threadIdx.x, lane = tid & 63, wid = tid >> 6;
  __shared__ int lcnt[512];
  __shared__ int wsum[8];
  __shared__ int base_s;
  if (tid < 64) {                                   // base = sum cnt[0..b)
    int s = 0;
    for (int t = tid; t < b; t += 64) s += cnt[t];
    #pragma unroll
    for (int d = 1; d < 64; d <<= 1) s += __shfl_xor(s, d);
    if (tid == 0) base_s = s;
  }
  lcnt[tid] = 0;
  __syncthreads();
  const int n = min(cnt[b], BKCAP);
  for (int i = tid; i < n; i += 512)
    atomicAdd(&lcnt[bkd[i] >> 17], 1);
  __syncthreads();
  int x = lcnt[tid];                                // per-row count
  int inc = x;
  #pragma unroll
  for (int d = 1; d < 64; d <<= 1) { int t = __shfl_up(inc, d); if (lane >= d) inc += t; }
  if (lane == 63) wsum[wid] = inc;
  __syncthreads();
  int wbase = 0;
  for (int k = 0; k < wid; k++) wbase += wsum[k];
  const int gpos = base_s + wbase + inc - x;        // global exclusive position for row tid
  const int row = (b << 9) + tid;
  if (row < NODES) off[row] = gpos;
  if (b == NBK - 1 && tid == 0) off[NODES] = NNZV;
  __syncthreads();
  lcnt[tid] = gpos;                                 // cursor = global position
  __syncthreads();
  for (int i = tid; i < n; i += 512) {
    unsigned e = bkd[i];
    int p = atomicAdd(&lcnt[e >> 17], 1);
    col[p] = (int)(e & 0x1FFFFu);
  }
}

// ======= MFMA GEMM: Y[M,N](bf16) = X[M,128] @ W[128,N]; WT is pre-transposed bf16 [N][128] =======
template<int N, bool XBF>
__global__ __launch_bounds__(256) void gemm_kernel(const void* __restrict__ Xv,
                                                   const u16* __restrict__ WT,
                                                   u16* __restrict__ Y, int M) {
  __shared__ u16 sX[64 * 136];
  __shared__ u16 sW[N * 136];
  const int tid = threadIdx.x, lane = tid & 63, w = tid >> 6;
  const int chunk = blockIdx.x * 64;
  constexpr int WV = N * 128 / 8;
  for (int t = tid; t < WV; t += 256) {
    int e = t * 8, n = e >> 7, k = e & 127;
    *(bf16x8*)(sW + n * 136 + k) = *(const bf16x8*)(WT + n * 128 + k);
  }
  if constexpr (XBF) {
    const u16* X = (const u16*)Xv;
    for (int t = tid; t < 1024; t += 256) {
      int e = t * 8, r = e >> 7, k = e & 127;
      int row = min(chunk + r, M - 1);
      *(bf16x8*)(sX + r * 136 + k) = *(const bf16x8*)(X + (size_t)row * 128 + k);
    }
  } else {
    const float* X = (const float*)Xv;
    for (int t = tid; t < 2048; t += 256) {
      int r = t >> 5, c4 = t & 31;
      int row = min(chunk + r, M - 1);
      float4 v = *(const float4*)(X + (size_t)row * 128 + c4 * 4);
      ushort4 o = { f2b(v.x), f2b(v.y), f2b(v.z), f2b(v.w) };
      *(ushort4*)(sX + r * 136 + c4 * 4) = o;
    }
  }
  __syncthreads();
  constexpr int CW = N / 2;
  constexpr int NT = CW / 16;
  const int wr = w >> 1, wc = w & 1;
  const int l15 = lane & 15;
  const int arow = wr * 32 + l15;
  const int kb = (lane >> 4) * 8;
  f32x4 acc[2][NT];
  #pragma unroll
  for (int rt = 0; rt < 2; rt++)
    #pragma unroll
    for (int nt = 0; nt < NT; nt++) acc[rt][nt] = (f32x4){0.f, 0.f, 0.f, 0.f};
  #pragma unroll
  for (int kk = 0; kk < 4; kk++) {
    const int ko = kk * 32 + kb;
    bf16x8 a0 = *(const bf16x8*)(sX + arow * 136 + ko);
    bf16x8 a1 = *(const bf16x8*)(sX + (arow + 16) * 136 + ko);
    #pragma unroll
    for (int nt = 0; nt < NT; nt++) {
      bf16x8 bb = *(const bf16x8*)(sW + (wc * CW + nt * 16 + l15) * 136 + ko);
      acc[0][nt] = __builtin_amdgcn_mfma_f32_16x16x32_bf16(a0, bb, acc[0][nt], 0, 0, 0);
      acc[1][nt] = __builtin_amdgcn_mfma_f32_16x16x32_bf16(a1, bb, acc[1][nt], 0, 0, 0);
    }
  }
  const int r4 = (lane >> 4) * 4;
  #pragma unroll
  for (int rt = 0; rt < 2; rt++)
    #pragma unroll
    for (int r = 0; r < 4; r++) {
      int row = chunk + wr * 32 + rt * 16 + r4 + r;
      if (row < M) {
        #pragma unroll
        for (int nt = 0; nt < NT; nt++)
          Y[(size_t)row * N + wc * CW + nt * 16 + l15] = f2b(acc[rt][nt][r]);
      }
    }
}

// ===== F=128 member-parallel gather (R8 structure): wave = 1 row =====
// lane = (member-slot g of 4, 16B feature-block l of 16); one VMEM = 4 member sub-rows.
template<bool HASB, bool RELU>
__global__ __launch_bounds__(256) void gather128_kernel(const int* __restrict__ off,
                                                        const int* __restrict__ col,
                                                        const u16* __restrict__ src,
                                                        const float* __restrict__ bias,
                                                        u16* __restrict__ dst, int nrows) {
  constexpr int G = 4, L = 16;
  const int row = blockIdx.x * 4 + (threadIdx.x >> 6);
  if (row >= nrows) return;
  const int lane = threadIdx.x & 63;
  const int g = lane / L;
  const int l = lane % L;
  const int s0 = off[row], s1 = off[row + 1];
  float acc[8] = {};
  int k = s0;
  for (; k + 4 * G <= s1; k += 4 * G) {
    int c0 = col[k + g];
    int c1 = col[k + G + g];
    int c2 = col[k + 2 * G + g];
    int c3 = col[k + 3 * G + g];
    bf16x8 v0 = *(const bf16x8*)(src + (size_t)c0 * 128 + l * 8);
    bf16x8 v1 = *(const bf16x8*)(src + (size_t)c1 * 128 + l * 8);
    bf16x8 v2 = *(const bf16x8*)(src + (size_t)c2 * 128 + l * 8);
    bf16x8 v3 = *(const bf16x8*)(src + (size_t)c3 * 128 + l * 8);
    #pragma unroll
    for (int t = 0; t < 8; t++) acc[t] += b2f((u16)v0[t]);
    #pragma unroll
    for (int t = 0; t < 8; t++) acc[t] += b2f((u16)v1[t]);
    #pragma unroll
    for (int t = 0; t < 8; t++) acc[t] += b2f((u16)v2[t]);
    #pragma unroll
    for (int t = 0; t < 8; t++) acc[t] += b2f((u16)v3[t]);
  }
  for (; k < s1; k += G) {
    int idx = k + g;
    int c = col[min(idx, s1 - 1)];
    bf16x8 v = *(const bf16x8*)(src + (size_t)c * 128 + l * 8);
    if (idx < s1) {
      #pragma unroll
      for (int t = 0; t < 8; t++) acc[t] += b2f((u16)v[t]);
    }
  }
  #pragma unroll
  for (int d = L; d < 64; d <<= 1) {
    #pragma unroll
    for (int t = 0; t < 8; t++) acc[t] += __shfl_xor(acc[t], d);
  }
  if (g == 0) {
    const float sc = (s1 > s0) ? 1.0f / (float)(s1 - s0) : 0.f;
    float v[8];
    #pragma unroll
    for (int t = 0; t < 8; t++) {
      v[t] = acc[t] * sc;
      if constexpr (HASB) v[t] += bias[l * 8 + t];
      if constexpr (RELU) v[t] = fmaxf(v[t], 0.f);
    }
    bf16x8 o;
    #pragma unroll
    for (int t = 0; t < 8; t++) o[t] = (short)f2b(v[t]);
    *(bf16x8*)(dst + (size_t)row * 128 + l * 8) = o;
  }
}

// ===== F=64 gather, 4 rows per wave (16 lanes/row: 2 slots x 8 feat-lanes) =====
template<bool HASB, bool F32OUT>
__global__ __launch_bounds__(256) void gather64_kernel(const int* __restrict__ off,
                                                       const int* __restrict__ col,
                                                       const u16* __restrict__ src,
                                                       const float* __restrict__ bias,
                                                       void* __restrict__ dstv, int nrows) {
  const int lane = threadIdx.x & 63, wave = threadIdx.x >> 6;
  const int rr = lane >> 4;               // row quarter (0..3)
  const int lr = lane & 15;
  const int slot = lr >> 3;               // member slot 0..1
  const int l = lr & 7;                   // 8-feat block
  const int row = blockIdx.x * 16 + wave * 4 + rr;
  const bool act = row < nrows;
  const int s0 = act ? off[row] : 0;
  const int s1 = act ? off[row + 1] : 0;
  float acc[8] = {};
  for (int k = s0; k < s1; k += 8) {      // 4 batches (2 slots x 4-deep) in flight
    const int i0 = k + slot, i1 = i0 + 2, i2 = i0 + 4, i3 = i0 + 6;
    const int c0 = col[min(i0, s1 - 1)];
    const int c1 = col[min(i1, s1 - 1)];
    const int c2 = col[min(i2, s1 - 1)];
    const int c3 = col[min(i3, s1 - 1)];
    bf16x8 v0 = *(const bf16x8*)(src + (size_t)c0 * 64 + l * 8);
    bf16x8 v1 = *(const bf16x8*)(src + (size_t)c1 * 64 + l * 8);
    bf16x8 v2 = *(const bf16x8*)(src + (size_t)c2 * 64 + l * 8);
    bf16x8 v3 = *(const bf16x8*)(src + (size_t)c3 * 64 + l * 8);
    if (i0 < s1) {
      #pragma unroll
      for (int t = 0; t < 8; t++) acc[t] += b2f((u16)v0[t]);
    }
    if (i1 < s1) {
      #pragma unroll
      for (int t = 0; t < 8; t++) acc[t] += b2f((u16)v1[t]);
    }
    if (i2 < s1) {
      #pragma unroll
      for (int t = 0; t < 8; t++) acc[t] += b2f((u16)v2[t]);
    }
    if (i3 < s1) {
      #pragma unroll
      for (int t = 0; t < 8; t++) acc[t] += b2f((u16)v3[t]);
    }
  }
  // reduce across the 2 member slots (lane^8 stays within the 16-lane row group)
  #pragma unroll
  for (int t = 0; t < 8; t++) acc[t] += __shfl_xor(acc[t], 8);
  if (slot == 0 && act) {
    const float sc = (s1 > s0) ? 1.0f / (float)(s1 - s0) : 0.f;
    float v[8];
    #pragma unroll
    for (int t = 0; t < 8; t++) {
      v[t] = acc[t] * sc;
      if constexpr (HASB) v[t] += bias[l * 8 + t];
    }
    if constexpr (F32OUT) {
      float* d = (float*)dstv + (size_t)row * 64 + l * 8;
      *(float4*)d = make_float4(v[0], v[1], v[2], v[3]);
      *(float4*)(d + 4) = make_float4(v[4], v[5], v[6], v[7]);
    } else {
      bf16x8 o;
      #pragma unroll
      for (int t = 0; t < 8; t++) o[t] = (short)f2b(v[t]);
      *(bf16x8*)((u16*)dstv + (size_t)row * 64 + l * 8) = o;
    }
  }
}

extern "C" void kernel_launch(void* const* d_in, const int* in_sizes, int n_in,
                              void* d_out, int out_size, void* d_ws, size_t ws_size,
                              hipStream_t stream) {
  const float* x  = (const float*)d_in[0];
  const int*   hi = (const int*)d_in[1];
  const float* W1 = (const float*)d_in[2];
  const float* b1 = (const float*)d_in[3];
  const float* W2 = (const float*)d_in[4];
  const float* b2 = (const float*)d_in[5];
  float* out = (float*)d_out;
  const int* nidx = hi;             // row 0: node indices
  const int* eidx = hi + NNZV;      // row 1: edge indices

  char* w = (char*)d_ws;
  int*      off_e = (int*)w;                           // 100001 ints
  int*      off_v = (int*)(w + 524288);                // 100001 ints
  int*      gcnt  = (int*)(w + 1048576);               // 392 ints
  u16*      W1T   = (u16*)(w + 1052672);               // 128x128 bf16
  u16*      W2T   = (u16*)(w + 1085440);               // 64x128 bf16
  int*      col_e = (int*)(w + 2097152);               // 1.6M ints
  int*      col_v = (int*)(w + 8650752);               // 1.6M ints
  unsigned* bk    = (unsigned*)(w + 16777216);         // 2*196*12288*4B = 19.3 MB
  u16*      bufH  = (u16*)(w + 56623104);              // 25.6 MB: h1, then h2, then m2e
  u16*      bufM  = (u16*)(w + 56623104 + 25600000);   // 25.6 MB: m_e, then g2

  // ---- weight pre-transpose + CSR build ----
  hipMemsetAsync(gcnt, 0, 392 * 4, stream);
  wtrans_kernel<<<96, 256, 0, stream>>>(W1, W2, W1T, W2T);
  partition_kernel<<<NTIL2, 256, 0, stream>>>(nidx, eidx, gcnt, bk);
  bucket_sort_kernel<<<2 * NBK, 512, 0, stream>>>(gcnt, bk, off_e, off_v, col_e, col_v);

  // ---- conv1 (F=128) ----
  gemm_kernel<128, false><<<1563, 256, 0, stream>>>(x, W1T, bufH, NODES);          // h1(bf16)
  gather128_kernel<false, false><<<(EDGES + 3) / 4, 256, 0, stream>>>(
      off_e, col_e, bufH, nullptr, bufM, EDGES);                                   // m_e
  gather128_kernel<true, true><<<(NODES + 3) / 4, 256, 0, stream>>>(
      off_v, col_v, bufM, b1, bufH, NODES);                                        // h2
  // ---- conv2 (F=64) ----
  gemm_kernel<64, true><<<1563, 256, 0, stream>>>(bufH, W2T, bufM, NODES);         // g2(bf16)
  gather64_kernel<false, false><<<(EDGES + 15) / 16, 256, 0, stream>>>(
      off_e, col_e, bufM, nullptr, bufH, EDGES);                                   // m2e
  gather64_kernel<true, true><<<(NODES + 15) / 16, 256, 0, stream>>>(
      off_v, col_v, bufH, b2, out, NODES);                                         // out(f32)
}